// Round 6
// baseline (879.773 us; speedup 1.0000x reference)
//
#include <hip/hip_runtime.h>

// ---------------- problem constants ----------------
#define BATCH 16
#define SEQ   1024
#define EMBED 1280
#define NH    16
#define HD    80
#define HDP   96           // HD padded to 3*32 for MFMA K-steps
#define NQKV  3840
#define MTOK  (BATCH*SEQ)  // 16384
#define SCALE 0.11180339887498948f
#define LOG2E 1.4426950408889634f

// LDS strides padded to kill bank conflicts (keep 16B alignment for b128 reads)
#define SK_STRIDE 104      // 52 dwords
#define SV_STRIDE 72       // 36 dwords
#define SP_STRIDE 72

typedef _Float16 half8 __attribute__((ext_vector_type(8)));
typedef _Float16 half4 __attribute__((ext_vector_type(4)));
typedef float floatx4 __attribute__((ext_vector_type(4)));

#define GLD_TO_LDS(gp, lp)                                                        \
  __builtin_amdgcn_global_load_lds(                                               \
      (const __attribute__((address_space(1))) void*)(gp),                        \
      (__attribute__((address_space(3))) void*)(lp), 16, 0, 0)

// 16-lane all-reduce max on the VALU pipe (DPP)
__device__ __forceinline__ float rowmax16(float x) {
#define DPP_MAX(ctrl)                                                             \
  {                                                                               \
    float y = __int_as_float(                                                     \
        __builtin_amdgcn_update_dpp(0, __float_as_int(x), ctrl, 0xF, 0xF, true)); \
    x = fmaxf(x, y);                                                              \
  }
  DPP_MAX(0xB1);   // quad_perm [1,0,3,2]  (xor1)
  DPP_MAX(0x4E);   // quad_perm [2,3,0,1]  (xor2)
  DPP_MAX(0x141);  // row_half_mirror      (xor4 after uniform mod 4)
  DPP_MAX(0x140);  // row_mirror           (xor8 after uniform mod 8)
#undef DPP_MAX
  return x;
}

// ---------------- converts ----------------
__global__ void cvt_f32_to_f16(const float4* __restrict__ in, _Float16* __restrict__ out, int n4) {
  int i = blockIdx.x * blockDim.x + threadIdx.x;
  if (i < n4) {
    float4 v = in[i];
    half4 h;
    h[0] = (_Float16)v.x; h[1] = (_Float16)v.y; h[2] = (_Float16)v.z; h[3] = (_Float16)v.w;
    *(half4*)(out + (size_t)i * 4) = h;
  }
}

// in [K=1280 x N] fp32 row-major -> out [N x 1280] f16, LDS-tiled (coalesced both sides)
template <int N>
__global__ void cvt_transpose_f16(const float* __restrict__ in, _Float16* __restrict__ out) {
  __shared__ float tile[32][33];
  const int tx = threadIdx.x & 31, ty = threadIdx.x >> 5;  // 256 thr: ty 0..7
  const int k0 = blockIdx.y * 32;
  const int n0 = blockIdx.x * 32;
#pragma unroll
  for (int j = 0; j < 4; ++j)
    tile[ty + 8 * j][tx] = in[(size_t)(k0 + ty + 8 * j) * N + n0 + tx];
  __syncthreads();
#pragma unroll
  for (int j = 0; j < 4; ++j)
    out[(size_t)(n0 + ty + 8 * j) * 1280 + k0 + tx] = (_Float16)tile[tx][ty + 8 * j];
}

// ---------------- 256x256 GEMM, 2 barriers/K-tile, wave-internal ds_read<->MFMA overlap ----
// (unchanged from R4 — verified; see R4 hazard ledger)

#define STAGE_A(H, T, D)                                                           \
  do {                                                                             \
    GLD_TO_LDS(aSrc0 + (size_t)((H) * 128) * 1280 + (T) * 64,                      \
               &sA[D][((H) * 128 + wave * 16) * 64]);                              \
    GLD_TO_LDS(aSrc0 + (size_t)((H) * 128 + 8) * 1280 + (T) * 64,                  \
               &sA[D][((H) * 128 + wave * 16 + 8) * 64]);                          \
  } while (0)

#define STAGE_B(H, T, D)                                                           \
  do {                                                                             \
    GLD_TO_LDS(bSrc0 + (size_t)((H) * 128) * 1280 + (T) * 64,                      \
               &sB[D][((H) * 128 + wave * 16) * 64]);                              \
    GLD_TO_LDS(bSrc0 + (size_t)((H) * 128 + 8) * 1280 + (T) * 64,                  \
               &sB[D][((H) * 128 + wave * 16 + 8) * 64]);                          \
  } while (0)

#define LDS_FRAG(P, ROWB, FR, KK) (*(const half8*)((P) + ((ROWB) + (FR) * 16) * 64 + cofs[KK]))

#define MFMA_Q(MIB, NIB)                                                           \
  _Pragma("unroll") for (int mi = 0; mi < 4; ++mi)                                 \
    _Pragma("unroll") for (int ni = 0; ni < 2; ++ni)                               \
      _Pragma("unroll") for (int kk = 0; kk < 2; ++kk)                             \
        acc[(MIB) + mi][(NIB) + ni] = __builtin_amdgcn_mfma_f32_16x16x32_f16(      \
            af[mi][kk], bf[(NIB) + ni][kk], acc[(MIB) + mi][(NIB) + ni], 0, 0, 0)

#define GBODY2(T, D, SA, SB, VNSTR)                                                \
  {                                                                                \
    const _Float16* pA = &sA[D][0];                                                \
    const _Float16* pB = &sB[D][0];                                                \
    if (SA) { STAGE_A(0, (T) + 1, (D) ^ 1); STAGE_A(1, (T) + 1, (D) ^ 1); }        \
    _Pragma("unroll") for (int mi = 0; mi < 4; ++mi)                               \
      _Pragma("unroll") for (int kk = 0; kk < 2; ++kk)                             \
        af[mi][kk] = LDS_FRAG(pA, rA, mi, kk);                                     \
    _Pragma("unroll") for (int ni = 0; ni < 4; ++ni)                               \
      _Pragma("unroll") for (int kk = 0; kk < 2; ++kk)                             \
        bf[ni][kk] = LDS_FRAG(pB, rB, ni, kk);                                     \
    __builtin_amdgcn_s_setprio(1);                                                 \
    MFMA_Q(0, 0);                                                                  \
    MFMA_Q(0, 2);                                                                  \
    __builtin_amdgcn_s_setprio(0);                                                 \
    _Pragma("unroll") for (int mi = 0; mi < 4; ++mi)                               \
      _Pragma("unroll") for (int kk = 0; kk < 2; ++kk)                             \
        af[mi][kk] = LDS_FRAG(pA, rA, 4 + mi, kk);                                 \
    __builtin_amdgcn_s_barrier();                                                  \
    if (SB) { STAGE_B(0, (T) + 2, (D)); STAGE_B(1, (T) + 2, (D)); }                \
    __builtin_amdgcn_s_setprio(1);                                                 \
    MFMA_Q(4, 0);                                                                  \
    MFMA_Q(4, 2);                                                                  \
    __builtin_amdgcn_s_setprio(0);                                                 \
    asm volatile("s_waitcnt " VNSTR ::: "memory");                                 \
    __builtin_amdgcn_s_barrier();                                                  \
  }

template <int MODE>
__global__ __launch_bounds__(512, 2)
void gemm256(const _Float16* __restrict__ A, const _Float16* __restrict__ Bt,
             const float* __restrict__ bias,
             _Float16* __restrict__ q_pad, _Float16* __restrict__ k_pad,
             _Float16* __restrict__ v_t, float* __restrict__ outf) {
  __shared__ __align__(16) _Float16 sA[2][256 * 64];  // 64 KiB
  __shared__ __align__(16) _Float16 sB[2][256 * 64];  // 64 KiB

  const int tid = threadIdx.x;
  const int wave = tid >> 6, lane = tid & 63, quad = lane >> 4, r16 = lane & 15;
  const int wm = wave >> 2, wn = wave & 3;

  // XCD-contiguous swizzle: 64 m-tiles = 8 XCDs x 8; grid %% 8 == 0 for both MODEs.
  const int pid = blockIdx.x;
  const int xcd = pid & 7, local = pid >> 3;
  const int mt = xcd * 8 + (local & 7);
  const int nt = local >> 3;
  const int m0 = mt * 256, n0 = nt * 256;

  // staging source: row_local = wave*16 + i*8 + (lane>>3); chunk = (lane&7) ^ (lane>>3)
  const int l8 = lane >> 3, cg = (lane & 7) ^ l8;
  const _Float16* aSrc0 = A + ((size_t)m0 + wave * 16 + l8) * 1280 + cg * 8;
  const _Float16* bSrc0 = Bt + ((size_t)n0 + wave * 16 + l8) * 1280 + cg * 8;

  // fragment read bases (row&7 == r16&7 since frag rows are 16-aligned + r16)
  const int rA = wm * 128 + r16;
  const int rB = wn * 64 + r16;
  const int cofs[2] = { ((0 + quad) ^ (r16 & 7)) * 8, ((4 + quad) ^ (r16 & 7)) * 8 };

  floatx4 acc[8][4] = {};
  half8 af[4][2], bf[4][2];

  // prologue: tile0 full + B(1); A(1) is staged in tile0's early slot
  STAGE_A(0, 0, 0); STAGE_A(1, 0, 0); STAGE_B(0, 0, 0); STAGE_B(1, 0, 0);
  STAGE_B(0, 1, 1); STAGE_B(1, 1, 1);
  asm volatile("s_waitcnt vmcnt(4)" ::: "memory");  // tile0 landed; B(1) may be in flight
  __builtin_amdgcn_s_barrier();

  for (int it = 0; it < 9; ++it) {
    GBODY2(2 * it, 0, true, true, "vmcnt(4)");
    GBODY2(2 * it + 1, 1, true, true, "vmcnt(4)");
  }
  GBODY2(18, 0, true, false, "vmcnt(0)");   // drain: A(19)+B(19) must land
  GBODY2(19, 1, false, false, "vmcnt(0)");

  // ---------------- epilogue ----------------
  if (MODE == 1) {
#pragma unroll
    for (int mi = 0; mi < 8; ++mi)
#pragma unroll
      for (int ni = 0; ni < 4; ++ni) {
        int n = n0 + wn * 64 + ni * 16 + r16;
        float bv = bias[n];
#pragma unroll
        for (int r = 0; r < 4; ++r) {
          int m = m0 + wm * 128 + mi * 16 + quad * 4 + r;
          outf[(size_t)m * EMBED + n] = acc[mi][ni][r] + bv;
        }
      }
  } else {
#pragma unroll
    for (int mi = 0; mi < 8; ++mi)
#pragma unroll
      for (int ni = 0; ni < 4; ++ni) {
        int n = n0 + wn * 64 + ni * 16 + r16;
        float bv = bias[n];
        int which = n / 1280;
        int rem = n - which * 1280;
        int h = rem / 80;
        int d = rem - h * 80;
        int mbase = m0 + wm * 128 + mi * 16 + quad * 4;  // 4-aligned, never crosses SEQ
        int b = mbase >> 10, s = mbase & 1023;
        int bh = b * NH + h;
        if (which == 2) {
          // v_t[bh][d][s]: 4 consecutive s per lane -> one 8B store (was 4x 2B scatter)
          half4 pv;
#pragma unroll
          for (int r = 0; r < 4; ++r) pv[r] = (_Float16)(acc[mi][ni][r] + bv);
          *(half4*)(v_t + ((size_t)bh * HD + d) * SEQ + s) = pv;
        } else {
          _Float16* dst = (which == 0) ? q_pad : k_pad;
#pragma unroll
          for (int r = 0; r < 4; ++r) {
            _Float16 val = (_Float16)(acc[mi][ni][r] + bv);
            dst[((size_t)bh * SEQ + (s + r)) * HDP + d] = val;
            if (d < 16) dst[((size_t)bh * SEQ + (s + r)) * HDP + 80 + d] = (_Float16)0.f;
          }
        }
      }
  }
}

// ---------------- flash attention (R6: single-buffer K/V, 2-sync iter, 4 blocks/CU) ----
// Latency-bound diagnosis (R5): VALU 47% / MFMA 23% / Occ 21% (2 blocks/CU, LDS-gated).
// Fix: drop the K/V double-buffer (TLP replaces intra-block overlap). LDS 63.5 -> 35.5 KB
// -> 4 blocks/CU (16 waves). Iter structure (2 syncs):
//   top: store V[kt] (regs from prev iter) ; issue K[kt+1], V[kt+1] loads
//   QK^T (reads sK only)  ;  softmax(mi0)
//   mid-sync  (publishes sV; all QK^T done -> sK free)
//   store K[kt+1] ; PV(mi0) ; softmax(mi1) [VALU overlaps PV MFMA] ; PV(mi1)
//   end-sync  (publishes sK; PV done -> sV free)
// Hazards: sV WAR (end-sync kt-1 before top store), sV RAW (mid-sync before PV),
// sK WAR (mid-sync after QK^T before store), sK RAW (end-sync before next QK^T).
// tv regs: store-before-reload enforces register WAR; lifetime = one iter.
__global__ __launch_bounds__(256, 4)
void attn_kernel(const _Float16* __restrict__ q_pad, const _Float16* __restrict__ k_pad,
                 const _Float16* __restrict__ v_t, _Float16* __restrict__ attn_out) {
  __shared__ __align__(16) _Float16 sK[64 * SK_STRIDE];      // 13.0 KB
  __shared__ __align__(16) _Float16 sV[96 * SV_STRIDE];      // 13.5 KB (rows 80..95 static)
  __shared__ __align__(16) _Float16 sP[4][16 * SP_STRIDE];   //  9.0 KB (per-wave, reused)

  const int tid = threadIdx.x;
  const int wave = tid >> 6, lane = tid & 63, quad = lane >> 4, r16 = lane & 15;
  const int bh = blockIdx.x & 255;         // bh-major: same bh -> same XCD (R5, keep)
  const int q0 = (blockIdx.x >> 8) * 128;

  // static sV rows 80..95 (ones row + zeros), written once; never overwritten in-loop
  if (tid < 128) {
    int row = 80 + (tid >> 3), col = (tid & 7) * 8;
    half8 z;
#pragma unroll
    for (int j = 0; j < 8; ++j) z[j] = (row == 80) ? (_Float16)1.f : (_Float16)0.f;
    *(half8*)(&sV[row * SV_STRIDE + col]) = z;
  }

  // Q fragments (A-layout), pre-scaled by SCALE*LOG2E (log2-domain softmax)
  half8 qf[2][3];
#pragma unroll
  for (int mi = 0; mi < 2; ++mi) {
    const _Float16* qb = q_pad + ((size_t)bh * SEQ + q0 + wave * 32 + mi * 16 + r16) * HDP;
#pragma unroll
    for (int kq = 0; kq < 3; ++kq) {
      half8 q = *(const half8*)(qb + kq * 32 + quad * 8);
#pragma unroll
      for (int j = 0; j < 8; ++j) q[j] = q[j] * (_Float16)(SCALE * LOG2E);
      qf[mi][kq] = q;
    }
  }

  // per-thread staging slots
  int rowK[3], colK[3];
#pragma unroll
  for (int i = 0; i < 3; ++i) {
    int c = tid + i * 256;
    rowK[i] = c / 12; colK[i] = c - rowK[i] * 12;
  }
  const int rowV0 = tid >> 3, colV0 = tid & 7;
  const _Float16* kgb = k_pad + ((size_t)bh * SEQ) * HDP;
  const _Float16* vgb = v_t + (size_t)bh * HD * SEQ;

  // prologue: load + store tile 0 (exposed latency once)
  uint4 tk0, tk1, tk2, tv0, tv1, tv2;
  {
    tk0 = *(const uint4*)(kgb + (size_t)(rowK[0]) * HDP + colK[0] * 8);
    tk1 = *(const uint4*)(kgb + (size_t)(rowK[1]) * HDP + colK[1] * 8);
    tk2 = *(const uint4*)(kgb + (size_t)(rowK[2]) * HDP + colK[2] * 8);
    tv0 = *(const uint4*)(vgb + (size_t)(rowV0) * SEQ + colV0 * 8);
    tv1 = *(const uint4*)(vgb + (size_t)(rowV0 + 32) * SEQ + colV0 * 8);
    *(uint4*)(&sK[rowK[0] * SK_STRIDE + colK[0] * 8]) = tk0;
    *(uint4*)(&sK[rowK[1] * SK_STRIDE + colK[1] * 8]) = tk1;
    *(uint4*)(&sK[rowK[2] * SK_STRIDE + colK[2] * 8]) = tk2;
    *(uint4*)(&sV[(rowV0)*SV_STRIDE + colV0 * 8]) = tv0;
    *(uint4*)(&sV[(rowV0 + 32) * SV_STRIDE + colV0 * 8]) = tv1;
    if (tid < 128) {
      tv2 = *(const uint4*)(vgb + (size_t)(rowV0 + 64) * SEQ + colV0 * 8);
      *(uint4*)(&sV[(rowV0 + 64) * SV_STRIDE + colV0 * 8]) = tv2;
    }
  }

  floatx4 o[2][6] = {};
  float mrow[2][4];
#pragma unroll
  for (int mi = 0; mi < 2; ++mi)
#pragma unroll
    for (int r = 0; r < 4; ++r) mrow[mi][r] = -1e30f;

  __syncthreads();  // tile0 + static rows visible

  for (int kt = 0; kt < 16; ++kt) {
    // ---- top: issue K[kt+1]; store V[kt] (kt>0; kt==0 stored in prologue); issue V[kt+1]
    if (kt < 15) {
      const int kb = (kt + 1) * 64;
      tk0 = *(const uint4*)(kgb + (size_t)(kb + rowK[0]) * HDP + colK[0] * 8);
      tk1 = *(const uint4*)(kgb + (size_t)(kb + rowK[1]) * HDP + colK[1] * 8);
      tk2 = *(const uint4*)(kgb + (size_t)(kb + rowK[2]) * HDP + colK[2] * 8);
    }
    if (kt > 0) {
      *(uint4*)(&sV[(rowV0)*SV_STRIDE + colV0 * 8]) = tv0;
      *(uint4*)(&sV[(rowV0 + 32) * SV_STRIDE + colV0 * 8]) = tv1;
      if (tid < 128)
        *(uint4*)(&sV[(rowV0 + 64) * SV_STRIDE + colV0 * 8]) = tv2;
    }
    if (kt < 15) {
      const int kb = (kt + 1) * 64;
      tv0 = *(const uint4*)(vgb + (size_t)(rowV0)*SEQ + kb + colV0 * 8);
      tv1 = *(const uint4*)(vgb + (size_t)(rowV0 + 32) * SEQ + kb + colV0 * 8);
      if (tid < 128)
        tv2 = *(const uint4*)(vgb + (size_t)(rowV0 + 64) * SEQ + kb + colV0 * 8);
    }

    // ---- S = Q K^T : 32 q-rows x 64 keys per wave (reads sK only)
    floatx4 sacc[2][4] = {};
    __builtin_amdgcn_s_setprio(1);
#pragma unroll
    for (int ni = 0; ni < 4; ++ni)
#pragma unroll
      for (int kq = 0; kq < 3; ++kq) {
        half8 kf = *(const half8*)(&sK[(ni * 16 + r16) * SK_STRIDE + kq * 32 + quad * 8]);
#pragma unroll
        for (int mi = 0; mi < 2; ++mi)
          sacc[mi][ni] = __builtin_amdgcn_mfma_f32_16x16x32_f16(qf[mi][kq], kf, sacc[mi][ni], 0, 0, 0);
      }
    __builtin_amdgcn_s_setprio(0);

    // ---- softmax mi=0 (log2 domain, strict defer-rescale) before mid-sync
#define SOFTMAX_MI(mi)                                                             \
    _Pragma("unroll") for (int r = 0; r < 4; ++r) {                                \
      float mx = fmaxf(fmaxf(sacc[mi][0][r], sacc[mi][1][r]),                      \
                       fmaxf(sacc[mi][2][r], sacc[mi][3][r]));                     \
      mx = rowmax16(mx);                                                           \
      if (mx > mrow[mi][r]) {                                                      \
        float alpha = __builtin_amdgcn_exp2f(mrow[mi][r] - mx);                    \
        mrow[mi][r] = mx;                                                          \
        _Pragma("unroll") for (int di = 0; di < 6; ++di) o[mi][di][r] *= alpha;    \
      }                                                                            \
      float m = mrow[mi][r];                                                       \
      _Pragma("unroll") for (int ni = 0; ni < 4; ++ni)                             \
        sacc[mi][ni][r] = __builtin_amdgcn_exp2f(sacc[mi][ni][r] - m);             \
    }

#define TRANSP_PV_MI(mi)                                                           \
    {                                                                              \
      _Pragma("unroll") for (int ni = 0; ni < 4; ++ni)                             \
        _Pragma("unroll") for (int r = 0; r < 4; ++r)                              \
          sP[wave][(quad * 4 + r) * SP_STRIDE + ni * 16 + r16] =                   \
              (_Float16)sacc[mi][ni][r];                                           \
      _Pragma("unroll") for (int kp = 0; kp < 2; ++kp) {                           \
        half8 pf = *(const half8*)(&sP[wave][r16 * SP_STRIDE + kp * 32 + quad * 8]); \
        __builtin_amdgcn_s_setprio(1);                                             \
        _Pragma("unroll") for (int di = 0; di < 6; ++di) {                         \
          half8 vf = *(const half8*)(&sV[(di * 16 + r16) * SV_STRIDE + kp * 32 + quad * 8]); \
          o[mi][di] = __builtin_amdgcn_mfma_f32_16x16x32_f16(pf, vf, o[mi][di], 0, 0, 0); \
        }                                                                          \
        __builtin_amdgcn_s_setprio(0);                                             \
      }                                                                            \
    }

    SOFTMAX_MI(0)

    __syncthreads();  // publishes sV (V[kt]); all QK^T done -> sK free

    // ---- store K[kt+1] into sK (published by end-sync for next iter's QK^T)
    if (kt < 15) {
      *(uint4*)(&sK[rowK[0] * SK_STRIDE + colK[0] * 8]) = tk0;
      *(uint4*)(&sK[rowK[1] * SK_STRIDE + colK[1] * 8]) = tk1;
      *(uint4*)(&sK[rowK[2] * SK_STRIDE + colK[2] * 8]) = tk2;
    }

    // ---- PV mi=0, then softmax mi=1 (VALU overlaps PV-mi0 MFMA drain), PV mi=1
    TRANSP_PV_MI(0)
    SOFTMAX_MI(1)
    TRANSP_PV_MI(1)

    __syncthreads();  // publishes sK; PV done -> sV free for next top store
  }

  // epilogue: l = o[mi][5] col 80 lives in r16==0 lane of each 16-group
  const int b = bh >> 4, h = bh & 15;
#pragma unroll
  for (int mi = 0; mi < 2; ++mi)
#pragma unroll
    for (int r = 0; r < 4; ++r) {
      float l = __shfl(o[mi][5][r], lane & 48);
      float inv = 1.0f / l;
      int tok = b * SEQ + q0 + wave * 32 + mi * 16 + quad * 4 + r;
#pragma unroll
      for (int di = 0; di < 5; ++di) {
        int e = h * HD + di * 16 + r16;
        attn_out[(size_t)tok * EMBED + e] = (_Float16)(o[mi][di][r] * inv);
      }
    }
}

// ---------------- launch ----------------
extern "C" void kernel_launch(void* const* d_in, const int* in_sizes, int n_in,
                              void* d_out, int out_size, void* d_ws, size_t ws_size,
                              hipStream_t stream) {
  const float* hidden = (const float*)d_in[0];
  const float* w_qkv  = (const float*)d_in[1];
  const float* b_qkv  = (const float*)d_in[2];
  const float* w_proj = (const float*)d_in[3];
  const float* b_proj = (const float*)d_in[4];
  float* out = (float*)d_out;

  char* ws = (char*)d_ws;
  size_t off = 0;
  _Float16* hidden_h = (_Float16*)(ws + off); off += (size_t)MTOK * EMBED * 2;
  _Float16* wqkv_t   = (_Float16*)(ws + off); off += (size_t)NQKV * EMBED * 2;
  _Float16* wproj_t  = (_Float16*)(ws + off); off += (size_t)EMBED * EMBED * 2;
  _Float16* q_pad    = (_Float16*)(ws + off); off += (size_t)BATCH * NH * SEQ * HDP * 2;
  _Float16* k_pad    = (_Float16*)(ws + off); off += (size_t)BATCH * NH * SEQ * HDP * 2;
  _Float16* v_t      = (_Float16*)(ws + off); off += (size_t)BATCH * NH * HD * SEQ * 2;
  _Float16* attn_out = hidden_h;  // alias: hidden_h consumed before attention writes

  {
    int n4 = MTOK * EMBED / 4;
    cvt_f32_to_f16<<<(n4 + 255) / 256, 256, 0, stream>>>((const float4*)hidden, hidden_h, n4);
  }
  cvt_transpose_f16<NQKV><<<dim3(NQKV / 32, 1280 / 32), 256, 0, stream>>>(w_qkv, wqkv_t);
  cvt_transpose_f16<EMBED><<<dim3(EMBED / 32, 1280 / 32), 256, 0, stream>>>(w_proj, wproj_t);

  // QKV projection: M=16384, N=3840 -> 64 x 15 = 960 blocks (960 % 8 == 0)
  gemm256<0><<<960, 512, 0, stream>>>(hidden_h, wqkv_t, b_qkv, q_pad, k_pad, v_t, nullptr);

  attn_kernel<<<BATCH * NH * (SEQ / 128), 256, 0, stream>>>(q_pad, k_pad, v_t, attn_out);

  // output projection: M=16384, N=1280 -> 64 x 5 = 320 blocks (320 % 8 == 0)
  gemm256<1><<<320, 512, 0, stream>>>(attn_out, wproj_t, b_proj, nullptr, nullptr, nullptr, out);
}

// Round 7
// 594.079 us; speedup vs baseline: 1.4809x; 1.4809x over previous
//
#include <hip/hip_runtime.h>

// ---------------- problem constants ----------------
#define BATCH 16
#define SEQ   1024
#define EMBED 1280
#define NH    16
#define HD    80
#define HDP   96           // HD padded to 3*32 for MFMA K-steps
#define NQKV  3840
#define MTOK  (BATCH*SEQ)  // 16384
#define SCALE 0.11180339887498948f
#define LOG2E 1.4426950408889634f

// LDS strides padded to kill bank conflicts (keep 16B alignment for b128 reads)
#define SK_STRIDE 104      // 52 dwords
#define SV_STRIDE 72       // 36 dwords
#define SP_STRIDE 72

typedef _Float16 half8 __attribute__((ext_vector_type(8)));
typedef _Float16 half4 __attribute__((ext_vector_type(4)));
typedef float floatx4 __attribute__((ext_vector_type(4)));

#define GLD_TO_LDS(gp, lp)                                                        \
  __builtin_amdgcn_global_load_lds(                                               \
      (const __attribute__((address_space(1))) void*)(gp),                        \
      (__attribute__((address_space(3))) void*)(lp), 16, 0, 0)

// 16-lane all-reduce max on the VALU pipe (DPP)
__device__ __forceinline__ float rowmax16(float x) {
#define DPP_MAX(ctrl)                                                             \
  {                                                                               \
    float y = __int_as_float(                                                     \
        __builtin_amdgcn_update_dpp(0, __float_as_int(x), ctrl, 0xF, 0xF, true)); \
    x = fmaxf(x, y);                                                              \
  }
  DPP_MAX(0xB1);   // quad_perm [1,0,3,2]  (xor1)
  DPP_MAX(0x4E);   // quad_perm [2,3,0,1]  (xor2)
  DPP_MAX(0x141);  // row_half_mirror      (xor4 after uniform mod 4)
  DPP_MAX(0x140);  // row_mirror           (xor8 after uniform mod 8)
#undef DPP_MAX
  return x;
}

// ---------------- converts ----------------
__global__ void cvt_f32_to_f16(const float4* __restrict__ in, _Float16* __restrict__ out, int n4) {
  int i = blockIdx.x * blockDim.x + threadIdx.x;
  if (i < n4) {
    float4 v = in[i];
    half4 h;
    h[0] = (_Float16)v.x; h[1] = (_Float16)v.y; h[2] = (_Float16)v.z; h[3] = (_Float16)v.w;
    *(half4*)(out + (size_t)i * 4) = h;
  }
}

// in [K=1280 x N] fp32 row-major -> out [N x 1280] f16, LDS-tiled (coalesced both sides)
template <int N>
__global__ void cvt_transpose_f16(const float* __restrict__ in, _Float16* __restrict__ out) {
  __shared__ float tile[32][33];
  const int tx = threadIdx.x & 31, ty = threadIdx.x >> 5;  // 256 thr: ty 0..7
  const int k0 = blockIdx.y * 32;
  const int n0 = blockIdx.x * 32;
#pragma unroll
  for (int j = 0; j < 4; ++j)
    tile[ty + 8 * j][tx] = in[(size_t)(k0 + ty + 8 * j) * N + n0 + tx];
  __syncthreads();
#pragma unroll
  for (int j = 0; j < 4; ++j)
    out[(size_t)(n0 + ty + 8 * j) * 1280 + k0 + tx] = (_Float16)tile[tx][ty + 8 * j];
}

// ---------------- 256x256 GEMM, 2 barriers/K-tile, wave-internal ds_read<->MFMA overlap ----
// (unchanged from R4 — verified; see R4 hazard ledger)

#define STAGE_A(H, T, D)                                                           \
  do {                                                                             \
    GLD_TO_LDS(aSrc0 + (size_t)((H) * 128) * 1280 + (T) * 64,                      \
               &sA[D][((H) * 128 + wave * 16) * 64]);                              \
    GLD_TO_LDS(aSrc0 + (size_t)((H) * 128 + 8) * 1280 + (T) * 64,                  \
               &sA[D][((H) * 128 + wave * 16 + 8) * 64]);                          \
  } while (0)

#define STAGE_B(H, T, D)                                                           \
  do {                                                                             \
    GLD_TO_LDS(bSrc0 + (size_t)((H) * 128) * 1280 + (T) * 64,                      \
               &sB[D][((H) * 128 + wave * 16) * 64]);                              \
    GLD_TO_LDS(bSrc0 + (size_t)((H) * 128 + 8) * 1280 + (T) * 64,                  \
               &sB[D][((H) * 128 + wave * 16 + 8) * 64]);                          \
  } while (0)

#define LDS_FRAG(P, ROWB, FR, KK) (*(const half8*)((P) + ((ROWB) + (FR) * 16) * 64 + cofs[KK]))

#define MFMA_Q(MIB, NIB)                                                           \
  _Pragma("unroll") for (int mi = 0; mi < 4; ++mi)                                 \
    _Pragma("unroll") for (int ni = 0; ni < 2; ++ni)                               \
      _Pragma("unroll") for (int kk = 0; kk < 2; ++kk)                             \
        acc[(MIB) + mi][(NIB) + ni] = __builtin_amdgcn_mfma_f32_16x16x32_f16(      \
            af[mi][kk], bf[(NIB) + ni][kk], acc[(MIB) + mi][(NIB) + ni], 0, 0, 0)

#define GBODY2(T, D, SA, SB, VNSTR)                                                \
  {                                                                                \
    const _Float16* pA = &sA[D][0];                                                \
    const _Float16* pB = &sB[D][0];                                                \
    if (SA) { STAGE_A(0, (T) + 1, (D) ^ 1); STAGE_A(1, (T) + 1, (D) ^ 1); }        \
    _Pragma("unroll") for (int mi = 0; mi < 4; ++mi)                               \
      _Pragma("unroll") for (int kk = 0; kk < 2; ++kk)                             \
        af[mi][kk] = LDS_FRAG(pA, rA, mi, kk);                                     \
    _Pragma("unroll") for (int ni = 0; ni < 4; ++ni)                               \
      _Pragma("unroll") for (int kk = 0; kk < 2; ++kk)                             \
        bf[ni][kk] = LDS_FRAG(pB, rB, ni, kk);                                     \
    __builtin_amdgcn_s_setprio(1);                                                 \
    MFMA_Q(0, 0);                                                                  \
    MFMA_Q(0, 2);                                                                  \
    __builtin_amdgcn_s_setprio(0);                                                 \
    _Pragma("unroll") for (int mi = 0; mi < 4; ++mi)                               \
      _Pragma("unroll") for (int kk = 0; kk < 2; ++kk)                             \
        af[mi][kk] = LDS_FRAG(pA, rA, 4 + mi, kk);                                 \
    __builtin_amdgcn_s_barrier();                                                  \
    if (SB) { STAGE_B(0, (T) + 2, (D)); STAGE_B(1, (T) + 2, (D)); }                \
    __builtin_amdgcn_s_setprio(1);                                                 \
    MFMA_Q(4, 0);                                                                  \
    MFMA_Q(4, 2);                                                                  \
    __builtin_amdgcn_s_setprio(0);                                                 \
    asm volatile("s_waitcnt " VNSTR ::: "memory");                                 \
    __builtin_amdgcn_s_barrier();                                                  \
  }

template <int MODE>
__global__ __launch_bounds__(512, 2)
void gemm256(const _Float16* __restrict__ A, const _Float16* __restrict__ Bt,
             const float* __restrict__ bias,
             _Float16* __restrict__ q_pad, _Float16* __restrict__ k_pad,
             _Float16* __restrict__ v_t, float* __restrict__ outf) {
  __shared__ __align__(16) _Float16 sA[2][256 * 64];  // 64 KiB
  __shared__ __align__(16) _Float16 sB[2][256 * 64];  // 64 KiB

  const int tid = threadIdx.x;
  const int wave = tid >> 6, lane = tid & 63, quad = lane >> 4, r16 = lane & 15;
  const int wm = wave >> 2, wn = wave & 3;

  // XCD-contiguous swizzle: 64 m-tiles = 8 XCDs x 8; grid %% 8 == 0 for both MODEs.
  const int pid = blockIdx.x;
  const int xcd = pid & 7, local = pid >> 3;
  const int mt = xcd * 8 + (local & 7);
  const int nt = local >> 3;
  const int m0 = mt * 256, n0 = nt * 256;

  // staging source: row_local = wave*16 + i*8 + (lane>>3); chunk = (lane&7) ^ (lane>>3)
  const int l8 = lane >> 3, cg = (lane & 7) ^ l8;
  const _Float16* aSrc0 = A + ((size_t)m0 + wave * 16 + l8) * 1280 + cg * 8;
  const _Float16* bSrc0 = Bt + ((size_t)n0 + wave * 16 + l8) * 1280 + cg * 8;

  // fragment read bases (row&7 == r16&7 since frag rows are 16-aligned + r16)
  const int rA = wm * 128 + r16;
  const int rB = wn * 64 + r16;
  const int cofs[2] = { ((0 + quad) ^ (r16 & 7)) * 8, ((4 + quad) ^ (r16 & 7)) * 8 };

  floatx4 acc[8][4] = {};
  half8 af[4][2], bf[4][2];

  // prologue: tile0 full + B(1); A(1) is staged in tile0's early slot
  STAGE_A(0, 0, 0); STAGE_A(1, 0, 0); STAGE_B(0, 0, 0); STAGE_B(1, 0, 0);
  STAGE_B(0, 1, 1); STAGE_B(1, 1, 1);
  asm volatile("s_waitcnt vmcnt(4)" ::: "memory");  // tile0 landed; B(1) may be in flight
  __builtin_amdgcn_s_barrier();

  for (int it = 0; it < 9; ++it) {
    GBODY2(2 * it, 0, true, true, "vmcnt(4)");
    GBODY2(2 * it + 1, 1, true, true, "vmcnt(4)");
  }
  GBODY2(18, 0, true, false, "vmcnt(0)");   // drain: A(19)+B(19) must land
  GBODY2(19, 1, false, false, "vmcnt(0)");

  // ---------------- epilogue ----------------
  if (MODE == 1) {
#pragma unroll
    for (int mi = 0; mi < 8; ++mi)
#pragma unroll
      for (int ni = 0; ni < 4; ++ni) {
        int n = n0 + wn * 64 + ni * 16 + r16;
        float bv = bias[n];
#pragma unroll
        for (int r = 0; r < 4; ++r) {
          int m = m0 + wm * 128 + mi * 16 + quad * 4 + r;
          outf[(size_t)m * EMBED + n] = acc[mi][ni][r] + bv;
        }
      }
  } else {
#pragma unroll
    for (int mi = 0; mi < 8; ++mi)
#pragma unroll
      for (int ni = 0; ni < 4; ++ni) {
        int n = n0 + wn * 64 + ni * 16 + r16;
        float bv = bias[n];
        int which = n / 1280;
        int rem = n - which * 1280;
        int h = rem / 80;
        int d = rem - h * 80;
        int mbase = m0 + wm * 128 + mi * 16 + quad * 4;  // 4-aligned, never crosses SEQ
        int b = mbase >> 10, s = mbase & 1023;
        int bh = b * NH + h;
        if (which == 2) {
          // v_t[bh][d][s]: 4 consecutive s per lane -> one 8B store (was 4x 2B scatter)
          half4 pv;
#pragma unroll
          for (int r = 0; r < 4; ++r) pv[r] = (_Float16)(acc[mi][ni][r] + bv);
          *(half4*)(v_t + ((size_t)bh * HD + d) * SEQ + s) = pv;
        } else {
          _Float16* dst = (which == 0) ? q_pad : k_pad;
#pragma unroll
          for (int r = 0; r < 4; ++r) {
            _Float16 val = (_Float16)(acc[mi][ni][r] + bv);
            dst[((size_t)bh * SEQ + (s + r)) * HDP + d] = val;
            if (d < 16) dst[((size_t)bh * SEQ + (s + r)) * HDP + 80 + d] = (_Float16)0.f;
          }
        }
      }
  }
}

// ---------------- flash attention (R7: single-K + dbuf-V, 49KB LDS, 3 blocks/CU) ----
// R6 post-mortem: launch_bounds(256,4) + regs held across a full iter -> scratch spill
// (WRITE_SIZE 41->825 MB, VGPR 64). R7 keeps the occupancy goal but via LDS only:
// sK single (13.0K) + sV dbuf (27.0K) + sP (9.0K) = 49.0 KB -> 3 blocks/CU.
// launch_bounds(256,2): VGPR cap 256 -> compiler keeps R5's ~92-VGPR allocation, no spill.
// Register lifetimes identical to known-good R5: loads issued at iter top, stored
// mid-iter after sync1 -- never live across an iteration boundary.
// Iter (2 syncs):
//   top: issue K[kt+1], V[kt+1] loads (transient regs)
//   QK^T (reads sK = K[kt]) ; softmax(mi0)
//   sync1  -- all QK^T done -> sK writable; (sV[cur] was published by sync2(kt-1))
//   store K[kt+1]->sK ; store V[kt+1]->sV[nxt]
//   PV(mi0) on sV[cur] ; softmax(mi1) [VALU overlaps MFMA drain] ; PV(mi1)
//   sync2  -- publishes sK, sV[nxt] for iter kt+1
// Hazards: sK WAR (store after sync1), sK RAW (sync2 before QK^T(kt+1));
// sV[nxt] WAR (reader PV(kt-1) drained before sync2(kt-1) < sync1(kt)), sV RAW (sync2).
__global__ __launch_bounds__(256, 2)
void attn_kernel(const _Float16* __restrict__ q_pad, const _Float16* __restrict__ k_pad,
                 const _Float16* __restrict__ v_t, _Float16* __restrict__ attn_out) {
  __shared__ __align__(16) _Float16 sK[64 * SK_STRIDE];      // 13.0 KB (single buffer)
  __shared__ __align__(16) _Float16 sV[2][96 * SV_STRIDE];   // 27.0 KB (rows 80..95 static)
  __shared__ __align__(16) _Float16 sP[4][16 * SP_STRIDE];   //  9.0 KB (per-wave, reused)

  const int tid = threadIdx.x;
  const int wave = tid >> 6, lane = tid & 63, quad = lane >> 4, r16 = lane & 15;
  const int bh = blockIdx.x & 255;         // bh-major: same bh -> same XCD (R5, keep)
  const int q0 = (blockIdx.x >> 8) * 128;

  // static sV rows 80..95 (ones row + zeros) in BOTH buffers; never overwritten in-loop
  if (tid < 128) {
    int row = 80 + (tid >> 3), col = (tid & 7) * 8;
    half8 z;
#pragma unroll
    for (int j = 0; j < 8; ++j) z[j] = (row == 80) ? (_Float16)1.f : (_Float16)0.f;
    *(half8*)(&sV[0][row * SV_STRIDE + col]) = z;
    *(half8*)(&sV[1][row * SV_STRIDE + col]) = z;
  }

  // Q fragments (A-layout), pre-scaled by SCALE*LOG2E (log2-domain softmax)
  half8 qf[2][3];
#pragma unroll
  for (int mi = 0; mi < 2; ++mi) {
    const _Float16* qb = q_pad + ((size_t)bh * SEQ + q0 + wave * 32 + mi * 16 + r16) * HDP;
#pragma unroll
    for (int kq = 0; kq < 3; ++kq) {
      half8 q = *(const half8*)(qb + kq * 32 + quad * 8);
#pragma unroll
      for (int j = 0; j < 8; ++j) q[j] = q[j] * (_Float16)(SCALE * LOG2E);
      qf[mi][kq] = q;
    }
  }

  // per-thread staging slots
  int rowK[3], colK[3];
#pragma unroll
  for (int i = 0; i < 3; ++i) {
    int c = tid + i * 256;
    rowK[i] = c / 12; colK[i] = c - rowK[i] * 12;
  }
  const int rowV0 = tid >> 3, colV0 = tid & 7;
  const _Float16* kgb = k_pad + ((size_t)bh * SEQ) * HDP;
  const _Float16* vgb = v_t + (size_t)bh * HD * SEQ;

  // prologue: load + store tile 0 (K0 -> sK, V0 -> sV[0]); exposed latency once
  {
    uint4 tk0 = *(const uint4*)(kgb + (size_t)(rowK[0]) * HDP + colK[0] * 8);
    uint4 tk1 = *(const uint4*)(kgb + (size_t)(rowK[1]) * HDP + colK[1] * 8);
    uint4 tk2 = *(const uint4*)(kgb + (size_t)(rowK[2]) * HDP + colK[2] * 8);
    uint4 tv0 = *(const uint4*)(vgb + (size_t)(rowV0) * SEQ + colV0 * 8);
    uint4 tv1 = *(const uint4*)(vgb + (size_t)(rowV0 + 32) * SEQ + colV0 * 8);
    *(uint4*)(&sK[rowK[0] * SK_STRIDE + colK[0] * 8]) = tk0;
    *(uint4*)(&sK[rowK[1] * SK_STRIDE + colK[1] * 8]) = tk1;
    *(uint4*)(&sK[rowK[2] * SK_STRIDE + colK[2] * 8]) = tk2;
    *(uint4*)(&sV[0][(rowV0)*SV_STRIDE + colV0 * 8]) = tv0;
    *(uint4*)(&sV[0][(rowV0 + 32) * SV_STRIDE + colV0 * 8]) = tv1;
    if (tid < 128) {
      uint4 tv2 = *(const uint4*)(vgb + (size_t)(rowV0 + 64) * SEQ + colV0 * 8);
      *(uint4*)(&sV[0][(rowV0 + 64) * SV_STRIDE + colV0 * 8]) = tv2;
    }
  }

  floatx4 o[2][6] = {};
  float mrow[2][4];
#pragma unroll
  for (int mi = 0; mi < 2; ++mi)
#pragma unroll
    for (int r = 0; r < 4; ++r) mrow[mi][r] = -1e30f;

  __syncthreads();  // tile0 + static rows visible

  for (int kt = 0; kt < 16; ++kt) {
    const int cur = kt & 1, nxt = cur ^ 1;

    // issue-early: global loads for tile kt+1 (transient regs, consumed after sync1)
    uint4 tk0, tk1, tk2, tv0, tv1, tv2;
    if (kt < 15) {
      const int kb = (kt + 1) * 64;
      tk0 = *(const uint4*)(kgb + (size_t)(kb + rowK[0]) * HDP + colK[0] * 8);
      tk1 = *(const uint4*)(kgb + (size_t)(kb + rowK[1]) * HDP + colK[1] * 8);
      tk2 = *(const uint4*)(kgb + (size_t)(kb + rowK[2]) * HDP + colK[2] * 8);
      tv0 = *(const uint4*)(vgb + (size_t)(rowV0)*SEQ + kb + colV0 * 8);
      tv1 = *(const uint4*)(vgb + (size_t)(rowV0 + 32) * SEQ + kb + colV0 * 8);
      if (tid < 128)
        tv2 = *(const uint4*)(vgb + (size_t)(rowV0 + 64) * SEQ + kb + colV0 * 8);
    }

    // ---- S = Q K^T : 32 q-rows x 64 keys per wave (reads sK = K[kt])
    floatx4 sacc[2][4] = {};
    __builtin_amdgcn_s_setprio(1);
#pragma unroll
    for (int ni = 0; ni < 4; ++ni)
#pragma unroll
      for (int kq = 0; kq < 3; ++kq) {
        half8 kf = *(const half8*)(&sK[(ni * 16 + r16) * SK_STRIDE + kq * 32 + quad * 8]);
#pragma unroll
        for (int mi = 0; mi < 2; ++mi)
          sacc[mi][ni] = __builtin_amdgcn_mfma_f32_16x16x32_f16(qf[mi][kq], kf, sacc[mi][ni], 0, 0, 0);
      }
    __builtin_amdgcn_s_setprio(0);

#define SOFTMAX_MI(mi)                                                             \
    _Pragma("unroll") for (int r = 0; r < 4; ++r) {                                \
      float mx = fmaxf(fmaxf(sacc[mi][0][r], sacc[mi][1][r]),                      \
                       fmaxf(sacc[mi][2][r], sacc[mi][3][r]));                     \
      mx = rowmax16(mx);                                                           \
      if (mx > mrow[mi][r]) {                                                      \
        float alpha = __builtin_amdgcn_exp2f(mrow[mi][r] - mx);                    \
        mrow[mi][r] = mx;                                                          \
        _Pragma("unroll") for (int di = 0; di < 6; ++di) o[mi][di][r] *= alpha;    \
      }                                                                            \
      float m = mrow[mi][r];                                                       \
      _Pragma("unroll") for (int ni = 0; ni < 4; ++ni)                             \
        sacc[mi][ni][r] = __builtin_amdgcn_exp2f(sacc[mi][ni][r] - m);             \
    }

#define TRANSP_PV_MI(mi, VBUF)                                                     \
    {                                                                              \
      _Pragma("unroll") for (int ni = 0; ni < 4; ++ni)                             \
        _Pragma("unroll") for (int r = 0; r < 4; ++r)                              \
          sP[wave][(quad * 4 + r) * SP_STRIDE + ni * 16 + r16] =                   \
              (_Float16)sacc[mi][ni][r];                                           \
      _Pragma("unroll") for (int kp = 0; kp < 2; ++kp) {                           \
        half8 pf = *(const half8*)(&sP[wave][r16 * SP_STRIDE + kp * 32 + quad * 8]); \
        __builtin_amdgcn_s_setprio(1);                                             \
        _Pragma("unroll") for (int di = 0; di < 6; ++di) {                         \
          half8 vf = *(const half8*)(&sV[VBUF][(di * 16 + r16) * SV_STRIDE + kp * 32 + quad * 8]); \
          o[mi][di] = __builtin_amdgcn_mfma_f32_16x16x32_f16(pf, vf, o[mi][di], 0, 0, 0); \
        }                                                                          \
        __builtin_amdgcn_s_setprio(0);                                             \
      }                                                                            \
    }

    SOFTMAX_MI(0)

    __syncthreads();  // sync1: all QK^T done -> sK writable; sV[cur] already published

    // store next tile: K[kt+1] -> sK, V[kt+1] -> sV[nxt] (published by sync2)
    if (kt < 15) {
      *(uint4*)(&sK[rowK[0] * SK_STRIDE + colK[0] * 8]) = tk0;
      *(uint4*)(&sK[rowK[1] * SK_STRIDE + colK[1] * 8]) = tk1;
      *(uint4*)(&sK[rowK[2] * SK_STRIDE + colK[2] * 8]) = tk2;
      *(uint4*)(&sV[nxt][(rowV0)*SV_STRIDE + colV0 * 8]) = tv0;
      *(uint4*)(&sV[nxt][(rowV0 + 32) * SV_STRIDE + colV0 * 8]) = tv1;
      if (tid < 128)
        *(uint4*)(&sV[nxt][(rowV0 + 64) * SV_STRIDE + colV0 * 8]) = tv2;
    }

    // ---- PV mi=0 (sV[cur]), softmax mi=1 (VALU overlaps MFMA drain), PV mi=1
    TRANSP_PV_MI(0, cur)
    SOFTMAX_MI(1)
    TRANSP_PV_MI(1, cur)

    __syncthreads();  // sync2: publishes sK (K[kt+1]) + sV[nxt] (V[kt+1]); PV done
  }

  // epilogue: l = o[mi][5] col 80 lives in r16==0 lane of each 16-group
  const int b = bh >> 4, h = bh & 15;
#pragma unroll
  for (int mi = 0; mi < 2; ++mi)
#pragma unroll
    for (int r = 0; r < 4; ++r) {
      float l = __shfl(o[mi][5][r], lane & 48);
      float inv = 1.0f / l;
      int tok = b * SEQ + q0 + wave * 32 + mi * 16 + quad * 4 + r;
#pragma unroll
      for (int di = 0; di < 5; ++di) {
        int e = h * HD + di * 16 + r16;
        attn_out[(size_t)tok * EMBED + e] = (_Float16)(o[mi][di][r] * inv);
      }
    }
}

// ---------------- launch ----------------
extern "C" void kernel_launch(void* const* d_in, const int* in_sizes, int n_in,
                              void* d_out, int out_size, void* d_ws, size_t ws_size,
                              hipStream_t stream) {
  const float* hidden = (const float*)d_in[0];
  const float* w_qkv  = (const float*)d_in[1];
  const float* b_qkv  = (const float*)d_in[2];
  const float* w_proj = (const float*)d_in[3];
  const float* b_proj = (const float*)d_in[4];
  float* out = (float*)d_out;

  char* ws = (char*)d_ws;
  size_t off = 0;
  _Float16* hidden_h = (_Float16*)(ws + off); off += (size_t)MTOK * EMBED * 2;
  _Float16* wqkv_t   = (_Float16*)(ws + off); off += (size_t)NQKV * EMBED * 2;
  _Float16* wproj_t  = (_Float16*)(ws + off); off += (size_t)EMBED * EMBED * 2;
  _Float16* q_pad    = (_Float16*)(ws + off); off += (size_t)BATCH * NH * SEQ * HDP * 2;
  _Float16* k_pad    = (_Float16*)(ws + off); off += (size_t)BATCH * NH * SEQ * HDP * 2;
  _Float16* v_t      = (_Float16*)(ws + off); off += (size_t)BATCH * NH * HD * SEQ * 2;
  _Float16* attn_out = hidden_h;  // alias: hidden_h consumed before attention writes

  {
    int n4 = MTOK * EMBED / 4;
    cvt_f32_to_f16<<<(n4 + 255) / 256, 256, 0, stream>>>((const float4*)hidden, hidden_h, n4);
  }
  cvt_transpose_f16<NQKV><<<dim3(NQKV / 32, 1280 / 32), 256, 0, stream>>>(w_qkv, wqkv_t);
  cvt_transpose_f16<EMBED><<<dim3(EMBED / 32, 1280 / 32), 256, 0, stream>>>(w_proj, wproj_t);

  // QKV projection: M=16384, N=3840 -> 64 x 15 = 960 blocks (960 % 8 == 0)
  gemm256<0><<<960, 512, 0, stream>>>(hidden_h, wqkv_t, b_qkv, q_pad, k_pad, v_t, nullptr);

  attn_kernel<<<BATCH * NH * (SEQ / 128), 256, 0, stream>>>(q_pad, k_pad, v_t, attn_out);

  // output projection: M=16384, N=1280 -> 64 x 5 = 320 blocks (320 % 8 == 0)
  gemm256<1><<<320, 512, 0, stream>>>(attn_out, wproj_t, b_proj, nullptr, nullptr, nullptr, out);
}

// Round 8
// 562.781 us; speedup vs baseline: 1.5633x; 1.0556x over previous
//
#include <hip/hip_runtime.h>

// ---------------- problem constants ----------------
#define BATCH 16
#define SEQ   1024
#define EMBED 1280
#define NH    16
#define HD    80
#define HDP   96           // HD padded to 3*32 for MFMA K-steps
#define NQKV  3840
#define MTOK  (BATCH*SEQ)  // 16384
#define SCALE 0.11180339887498948f
#define LOG2E 1.4426950408889634f

// LDS strides padded to kill bank conflicts (keep 16B alignment for b128 reads)
#define SK_STRIDE 104      // 52 dwords
#define SV_STRIDE 72       // 36 dwords
#define SP_STRIDE 72

typedef _Float16 half8 __attribute__((ext_vector_type(8)));
typedef _Float16 half4 __attribute__((ext_vector_type(4)));
typedef float floatx4 __attribute__((ext_vector_type(4)));

#define GLD_TO_LDS(gp, lp)                                                        \
  __builtin_amdgcn_global_load_lds(                                               \
      (const __attribute__((address_space(1))) void*)(gp),                        \
      (__attribute__((address_space(3))) void*)(lp), 16, 0, 0)

// ---------------- converts ----------------
__global__ void cvt_f32_to_f16(const float4* __restrict__ in, _Float16* __restrict__ out, int n4) {
  int i = blockIdx.x * blockDim.x + threadIdx.x;
  if (i < n4) {
    float4 v = in[i];
    half4 h;
    h[0] = (_Float16)v.x; h[1] = (_Float16)v.y; h[2] = (_Float16)v.z; h[3] = (_Float16)v.w;
    *(half4*)(out + (size_t)i * 4) = h;
  }
}

// in [K=1280 x N] fp32 row-major -> out [N x 1280] f16, LDS-tiled (coalesced both sides)
template <int N>
__global__ void cvt_transpose_f16(const float* __restrict__ in, _Float16* __restrict__ out) {
  __shared__ float tile[32][33];
  const int tx = threadIdx.x & 31, ty = threadIdx.x >> 5;  // 256 thr: ty 0..7
  const int k0 = blockIdx.y * 32;
  const int n0 = blockIdx.x * 32;
#pragma unroll
  for (int j = 0; j < 4; ++j)
    tile[ty + 8 * j][tx] = in[(size_t)(k0 + ty + 8 * j) * N + n0 + tx];
  __syncthreads();
#pragma unroll
  for (int j = 0; j < 4; ++j)
    out[(size_t)(n0 + ty + 8 * j) * 1280 + k0 + tx] = (_Float16)tile[tx][ty + 8 * j];
}

// ---------------- 256x256 GEMM, 2 barriers/K-tile, wave-internal ds_read<->MFMA overlap ----
// (unchanged from R4 — verified; see R4 hazard ledger)

#define STAGE_A(H, T, D)                                                           \
  do {                                                                             \
    GLD_TO_LDS(aSrc0 + (size_t)((H) * 128) * 1280 + (T) * 64,                      \
               &sA[D][((H) * 128 + wave * 16) * 64]);                              \
    GLD_TO_LDS(aSrc0 + (size_t)((H) * 128 + 8) * 1280 + (T) * 64,                  \
               &sA[D][((H) * 128 + wave * 16 + 8) * 64]);                          \
  } while (0)

#define STAGE_B(H, T, D)                                                           \
  do {                                                                             \
    GLD_TO_LDS(bSrc0 + (size_t)((H) * 128) * 1280 + (T) * 64,                      \
               &sB[D][((H) * 128 + wave * 16) * 64]);                              \
    GLD_TO_LDS(bSrc0 + (size_t)((H) * 128 + 8) * 1280 + (T) * 64,                  \
               &sB[D][((H) * 128 + wave * 16 + 8) * 64]);                          \
  } while (0)

#define LDS_FRAG(P, ROWB, FR, KK) (*(const half8*)((P) + ((ROWB) + (FR) * 16) * 64 + cofs[KK]))

#define MFMA_Q(MIB, NIB)                                                           \
  _Pragma("unroll") for (int mi = 0; mi < 4; ++mi)                                 \
    _Pragma("unroll") for (int ni = 0; ni < 2; ++ni)                               \
      _Pragma("unroll") for (int kk = 0; kk < 2; ++kk)                             \
        acc[(MIB) + mi][(NIB) + ni] = __builtin_amdgcn_mfma_f32_16x16x32_f16(      \
            af[mi][kk], bf[(NIB) + ni][kk], acc[(MIB) + mi][(NIB) + ni], 0, 0, 0)

#define GBODY2(T, D, SA, SB, VNSTR)                                                \
  {                                                                                \
    const _Float16* pA = &sA[D][0];                                                \
    const _Float16* pB = &sB[D][0];                                                \
    if (SA) { STAGE_A(0, (T) + 1, (D) ^ 1); STAGE_A(1, (T) + 1, (D) ^ 1); }        \
    _Pragma("unroll") for (int mi = 0; mi < 4; ++mi)                               \
      _Pragma("unroll") for (int kk = 0; kk < 2; ++kk)                             \
        af[mi][kk] = LDS_FRAG(pA, rA, mi, kk);                                     \
    _Pragma("unroll") for (int ni = 0; ni < 4; ++ni)                               \
      _Pragma("unroll") for (int kk = 0; kk < 2; ++kk)                             \
        bf[ni][kk] = LDS_FRAG(pB, rB, ni, kk);                                     \
    __builtin_amdgcn_s_setprio(1);                                                 \
    MFMA_Q(0, 0);                                                                  \
    MFMA_Q(0, 2);                                                                  \
    __builtin_amdgcn_s_setprio(0);                                                 \
    _Pragma("unroll") for (int mi = 0; mi < 4; ++mi)                               \
      _Pragma("unroll") for (int kk = 0; kk < 2; ++kk)                             \
        af[mi][kk] = LDS_FRAG(pA, rA, 4 + mi, kk);                                 \
    __builtin_amdgcn_s_barrier();                                                  \
    if (SB) { STAGE_B(0, (T) + 2, (D)); STAGE_B(1, (T) + 2, (D)); }                \
    __builtin_amdgcn_s_setprio(1);                                                 \
    MFMA_Q(4, 0);                                                                  \
    MFMA_Q(4, 2);                                                                  \
    __builtin_amdgcn_s_setprio(0);                                                 \
    asm volatile("s_waitcnt " VNSTR ::: "memory");                                 \
    __builtin_amdgcn_s_barrier();                                                  \
  }

template <int MODE>
__global__ __launch_bounds__(512, 2)
void gemm256(const _Float16* __restrict__ A, const _Float16* __restrict__ Bt,
             const float* __restrict__ bias,
             _Float16* __restrict__ q_pad, _Float16* __restrict__ k_pad,
             _Float16* __restrict__ v_t, float* __restrict__ outf) {
  __shared__ __align__(16) _Float16 sA[2][256 * 64];  // 64 KiB
  __shared__ __align__(16) _Float16 sB[2][256 * 64];  // 64 KiB

  const int tid = threadIdx.x;
  const int wave = tid >> 6, lane = tid & 63, quad = lane >> 4, r16 = lane & 15;
  const int wm = wave >> 2, wn = wave & 3;

  // XCD-contiguous swizzle: 64 m-tiles = 8 XCDs x 8; grid %% 8 == 0 for both MODEs.
  const int pid = blockIdx.x;
  const int xcd = pid & 7, local = pid >> 3;
  const int mt = xcd * 8 + (local & 7);
  const int nt = local >> 3;
  const int m0 = mt * 256, n0 = nt * 256;

  // staging source: row_local = wave*16 + i*8 + (lane>>3); chunk = (lane&7) ^ (lane>>3)
  const int l8 = lane >> 3, cg = (lane & 7) ^ l8;
  const _Float16* aSrc0 = A + ((size_t)m0 + wave * 16 + l8) * 1280 + cg * 8;
  const _Float16* bSrc0 = Bt + ((size_t)n0 + wave * 16 + l8) * 1280 + cg * 8;

  // fragment read bases (row&7 == r16&7 since frag rows are 16-aligned + r16)
  const int rA = wm * 128 + r16;
  const int rB = wn * 64 + r16;
  const int cofs[2] = { ((0 + quad) ^ (r16 & 7)) * 8, ((4 + quad) ^ (r16 & 7)) * 8 };

  floatx4 acc[8][4] = {};
  half8 af[4][2], bf[4][2];

  // prologue: tile0 full + B(1); A(1) is staged in tile0's early slot
  STAGE_A(0, 0, 0); STAGE_A(1, 0, 0); STAGE_B(0, 0, 0); STAGE_B(1, 0, 0);
  STAGE_B(0, 1, 1); STAGE_B(1, 1, 1);
  asm volatile("s_waitcnt vmcnt(4)" ::: "memory");  // tile0 landed; B(1) may be in flight
  __builtin_amdgcn_s_barrier();

  for (int it = 0; it < 9; ++it) {
    GBODY2(2 * it, 0, true, true, "vmcnt(4)");
    GBODY2(2 * it + 1, 1, true, true, "vmcnt(4)");
  }
  GBODY2(18, 0, true, false, "vmcnt(0)");   // drain: A(19)+B(19) must land
  GBODY2(19, 1, false, false, "vmcnt(0)");

  // ---------------- epilogue ----------------
  if (MODE == 1) {
#pragma unroll
    for (int mi = 0; mi < 8; ++mi)
#pragma unroll
      for (int ni = 0; ni < 4; ++ni) {
        int n = n0 + wn * 64 + ni * 16 + r16;
        float bv = bias[n];
#pragma unroll
        for (int r = 0; r < 4; ++r) {
          int m = m0 + wm * 128 + mi * 16 + quad * 4 + r;
          outf[(size_t)m * EMBED + n] = acc[mi][ni][r] + bv;
        }
      }
  } else {
#pragma unroll
    for (int mi = 0; mi < 8; ++mi)
#pragma unroll
      for (int ni = 0; ni < 4; ++ni) {
        int n = n0 + wn * 64 + ni * 16 + r16;
        float bv = bias[n];
        int which = n / 1280;
        int rem = n - which * 1280;
        int h = rem / 80;
        int d = rem - h * 80;
        int mbase = m0 + wm * 128 + mi * 16 + quad * 4;  // 4-aligned, never crosses SEQ
        int b = mbase >> 10, s = mbase & 1023;
        int bh = b * NH + h;
        if (which == 2) {
          // v_t[bh][d][s]: 4 consecutive s per lane -> one 8B store (was 4x 2B scatter)
          half4 pv;
#pragma unroll
          for (int r = 0; r < 4; ++r) pv[r] = (_Float16)(acc[mi][ni][r] + bv);
          *(half4*)(v_t + ((size_t)bh * HD + d) * SEQ + s) = pv;
        } else {
          _Float16* dst = (which == 0) ? q_pad : k_pad;
#pragma unroll
          for (int r = 0; r < 4; ++r) {
            _Float16 val = (_Float16)(acc[mi][ni][r] + bv);
            dst[((size_t)bh * SEQ + (s + r)) * HDP + d] = val;
            if (d < 16) dst[((size_t)bh * SEQ + (s + r)) * HDP + 80 + d] = (_Float16)0.f;
          }
        }
      }
  }
}

// ---------------- flash attention (R8: swapped QK^T, DS-pipe diet) ----
// R7 diagnosis: DS pipe ~82% busy (744 cyc/wave-iter model vs 193us measured) -> cut DS.
// (1) SWAPPED QK^T: sacc = mfma(kf, qf) (A/B frag lane layouts identical for 16x16x32).
//     Output S^T: lane (quad,r16) holds P[q=r16][k=ni*16+quad*4+r] -> 4 consecutive k
//     per reg quad -> P-store = 8x ds_write_b64 (was 32x ds_write_b16); sP becomes
//     direct [q][k] (no transpose), pf read unchanged.
//     Softmax now per-lane: in-lane max over 16 + shfl_xor(16,32) all-reduce;
//     alpha redistributed to o-rows (q=quad*4+r) via 4 shfls per mi.
// (2) SHARED vf: build pf[2][2] in regs (write mi0 -> read pf0 -> write mi1 -> read pf1,
//     same-wave DS ordering), then ONE vf loop with both mi MFMAs: V reads 24 -> 12 b128.
// DS/wave-iter: 144(kf)+48(Pw)+48(pf)+144(vf)+72(staging)+~72(shfl) = ~530 vs 744.
// Structure/hazards identical to R7 (single sK + dbuf sV, 2 syncs; ledger in R7 notes).
__global__ __launch_bounds__(256, 2)
void attn_kernel(const _Float16* __restrict__ q_pad, const _Float16* __restrict__ k_pad,
                 const _Float16* __restrict__ v_t, _Float16* __restrict__ attn_out) {
  __shared__ __align__(16) _Float16 sK[64 * SK_STRIDE];      // 13.0 KB (single buffer)
  __shared__ __align__(16) _Float16 sV[2][96 * SV_STRIDE];   // 27.0 KB (rows 80..95 static)
  __shared__ __align__(16) _Float16 sP[4][16 * SP_STRIDE];   //  9.0 KB (per-wave [q][k])

  const int tid = threadIdx.x;
  const int wave = tid >> 6, lane = tid & 63, quad = lane >> 4, r16 = lane & 15;
  const int bh = blockIdx.x & 255;         // bh-major: same bh -> same XCD (R5, keep)
  const int q0 = (blockIdx.x >> 8) * 128;

  // static sV rows 80..95 (ones row + zeros) in BOTH buffers; never overwritten in-loop
  if (tid < 128) {
    int row = 80 + (tid >> 3), col = (tid & 7) * 8;
    half8 z;
#pragma unroll
    for (int j = 0; j < 8; ++j) z[j] = (row == 80) ? (_Float16)1.f : (_Float16)0.f;
    *(half8*)(&sV[0][row * SV_STRIDE + col]) = z;
    *(half8*)(&sV[1][row * SV_STRIDE + col]) = z;
  }

  // Q fragments, pre-scaled by SCALE*LOG2E (log2-domain softmax). Used as B-operand now.
  half8 qf[2][3];
#pragma unroll
  for (int mi = 0; mi < 2; ++mi) {
    const _Float16* qb = q_pad + ((size_t)bh * SEQ + q0 + wave * 32 + mi * 16 + r16) * HDP;
#pragma unroll
    for (int kq = 0; kq < 3; ++kq) {
      half8 q = *(const half8*)(qb + kq * 32 + quad * 8);
#pragma unroll
      for (int j = 0; j < 8; ++j) q[j] = q[j] * (_Float16)(SCALE * LOG2E);
      qf[mi][kq] = q;
    }
  }

  // per-thread staging slots
  int rowK[3], colK[3];
#pragma unroll
  for (int i = 0; i < 3; ++i) {
    int c = tid + i * 256;
    rowK[i] = c / 12; colK[i] = c - rowK[i] * 12;
  }
  const int rowV0 = tid >> 3, colV0 = tid & 7;
  const _Float16* kgb = k_pad + ((size_t)bh * SEQ) * HDP;
  const _Float16* vgb = v_t + (size_t)bh * HD * SEQ;

  // prologue: load + store tile 0 (K0 -> sK, V0 -> sV[0]); exposed latency once
  {
    uint4 tk0 = *(const uint4*)(kgb + (size_t)(rowK[0]) * HDP + colK[0] * 8);
    uint4 tk1 = *(const uint4*)(kgb + (size_t)(rowK[1]) * HDP + colK[1] * 8);
    uint4 tk2 = *(const uint4*)(kgb + (size_t)(rowK[2]) * HDP + colK[2] * 8);
    uint4 tv0 = *(const uint4*)(vgb + (size_t)(rowV0) * SEQ + colV0 * 8);
    uint4 tv1 = *(const uint4*)(vgb + (size_t)(rowV0 + 32) * SEQ + colV0 * 8);
    *(uint4*)(&sK[rowK[0] * SK_STRIDE + colK[0] * 8]) = tk0;
    *(uint4*)(&sK[rowK[1] * SK_STRIDE + colK[1] * 8]) = tk1;
    *(uint4*)(&sK[rowK[2] * SK_STRIDE + colK[2] * 8]) = tk2;
    *(uint4*)(&sV[0][(rowV0)*SV_STRIDE + colV0 * 8]) = tv0;
    *(uint4*)(&sV[0][(rowV0 + 32) * SV_STRIDE + colV0 * 8]) = tv1;
    if (tid < 128) {
      uint4 tv2 = *(const uint4*)(vgb + (size_t)(rowV0 + 64) * SEQ + colV0 * 8);
      *(uint4*)(&sV[0][(rowV0 + 64) * SV_STRIDE + colV0 * 8]) = tv2;
    }
  }

  floatx4 o[2][6] = {};
  float mrow[2] = {-1e30f, -1e30f};  // per-lane running max for q = r16 (one per mi)

  __syncthreads();  // tile0 + static rows visible

  for (int kt = 0; kt < 16; ++kt) {
    const int cur = kt & 1, nxt = cur ^ 1;

    // issue-early: global loads for tile kt+1 (transient regs, consumed after sync1)
    uint4 tk0, tk1, tk2, tv0, tv1, tv2;
    if (kt < 15) {
      const int kb = (kt + 1) * 64;
      tk0 = *(const uint4*)(kgb + (size_t)(kb + rowK[0]) * HDP + colK[0] * 8);
      tk1 = *(const uint4*)(kgb + (size_t)(kb + rowK[1]) * HDP + colK[1] * 8);
      tk2 = *(const uint4*)(kgb + (size_t)(kb + rowK[2]) * HDP + colK[2] * 8);
      tv0 = *(const uint4*)(vgb + (size_t)(rowV0)*SEQ + kb + colV0 * 8);
      tv1 = *(const uint4*)(vgb + (size_t)(rowV0 + 32) * SEQ + kb + colV0 * 8);
      if (tid < 128)
        tv2 = *(const uint4*)(vgb + (size_t)(rowV0 + 64) * SEQ + kb + colV0 * 8);
    }

    // ---- S^T = K Q^T (swapped operands): lane holds P[q=r16][k=ni*16+quad*4+r]
    floatx4 sacc[2][4] = {};
    __builtin_amdgcn_s_setprio(1);
#pragma unroll
    for (int ni = 0; ni < 4; ++ni)
#pragma unroll
      for (int kq = 0; kq < 3; ++kq) {
        half8 kf = *(const half8*)(&sK[(ni * 16 + r16) * SK_STRIDE + kq * 32 + quad * 8]);
#pragma unroll
        for (int mi = 0; mi < 2; ++mi)
          sacc[mi][ni] = __builtin_amdgcn_mfma_f32_16x16x32_f16(kf, qf[mi][kq], sacc[mi][ni], 0, 0, 0);
      }
    __builtin_amdgcn_s_setprio(0);

    // ---- softmax (log2 domain), per-lane q-row = r16; strict defer-rescale
    float alphav[2];
#pragma unroll
    for (int mi = 0; mi < 2; ++mi) {
      float mx = sacc[mi][0][0];
#pragma unroll
      for (int ni = 0; ni < 4; ++ni)
#pragma unroll
        for (int r = 0; r < 4; ++r) mx = fmaxf(mx, sacc[mi][ni][r]);
      mx = fmaxf(mx, __shfl_xor(mx, 16));
      mx = fmaxf(mx, __shfl_xor(mx, 32));
      float a = 1.0f;
      if (mx > mrow[mi]) { a = __builtin_amdgcn_exp2f(mrow[mi] - mx); mrow[mi] = mx; }
      alphav[mi] = a;
      float m = mrow[mi];
#pragma unroll
      for (int ni = 0; ni < 4; ++ni)
#pragma unroll
        for (int r = 0; r < 4; ++r)
          sacc[mi][ni][r] = __builtin_amdgcn_exp2f(sacc[mi][ni][r] - m);
    }

    __syncthreads();  // sync1: all QK^T done -> sK writable; sV[cur] already published

    // store next tile: K[kt+1] -> sK, V[kt+1] -> sV[nxt] (published by sync2)
    if (kt < 15) {
      *(uint4*)(&sK[rowK[0] * SK_STRIDE + colK[0] * 8]) = tk0;
      *(uint4*)(&sK[rowK[1] * SK_STRIDE + colK[1] * 8]) = tk1;
      *(uint4*)(&sK[rowK[2] * SK_STRIDE + colK[2] * 8]) = tk2;
      *(uint4*)(&sV[nxt][(rowV0)*SV_STRIDE + colV0 * 8]) = tv0;
      *(uint4*)(&sV[nxt][(rowV0 + 32) * SV_STRIDE + colV0 * 8]) = tv1;
      if (tid < 128)
        *(uint4*)(&sV[nxt][(rowV0 + 64) * SV_STRIDE + colV0 * 8]) = tv2;
    }

    // ---- o-rescale: alpha lives at lane with l&15 == q; o rows are q = quad*4+r
#pragma unroll
    for (int mi = 0; mi < 2; ++mi)
#pragma unroll
      for (int r = 0; r < 4; ++r) {
        float ar = __shfl(alphav[mi], (lane & 48) + quad * 4 + r);
#pragma unroll
        for (int di = 0; di < 6; ++di) o[mi][di][r] *= ar;
      }

    // ---- P store ([q][k] direct, b64) + pf reads; same-wave DS ordering:
    // write mi0 -> read pf0 -> write mi1 -> read pf1 (sP rows reused across mi)
    half8 pf[2][2];
#pragma unroll
    for (int mi = 0; mi < 2; ++mi) {
#pragma unroll
      for (int ni = 0; ni < 4; ++ni) {
        half4 pp;
#pragma unroll
        for (int r = 0; r < 4; ++r) pp[r] = (_Float16)sacc[mi][ni][r];
        *(half4*)(&sP[wave][r16 * SP_STRIDE + ni * 16 + quad * 4]) = pp;
      }
#pragma unroll
      for (int kp = 0; kp < 2; ++kp)
        pf[mi][kp] = *(const half8*)(&sP[wave][r16 * SP_STRIDE + kp * 32 + quad * 8]);
    }

    // ---- PV with vf shared across both mi (12 b128 V-reads instead of 24)
#pragma unroll
    for (int kp = 0; kp < 2; ++kp) {
      __builtin_amdgcn_s_setprio(1);
#pragma unroll
      for (int di = 0; di < 6; ++di) {
        half8 vf = *(const half8*)(&sV[cur][(di * 16 + r16) * SV_STRIDE + kp * 32 + quad * 8]);
        o[0][di] = __builtin_amdgcn_mfma_f32_16x16x32_f16(pf[0][kp], vf, o[0][di], 0, 0, 0);
        o[1][di] = __builtin_amdgcn_mfma_f32_16x16x32_f16(pf[1][kp], vf, o[1][di], 0, 0, 0);
      }
      __builtin_amdgcn_s_setprio(0);
    }

    __syncthreads();  // sync2: publishes sK (K[kt+1]) + sV[nxt] (V[kt+1]); PV done
  }

  // epilogue: l = o[mi][5] col 80 lives in r16==0 lane of each 16-group
  const int b = bh >> 4, h = bh & 15;
#pragma unroll
  for (int mi = 0; mi < 2; ++mi)
#pragma unroll
    for (int r = 0; r < 4; ++r) {
      float l = __shfl(o[mi][5][r], lane & 48);
      float inv = 1.0f / l;
      int tok = b * SEQ + q0 + wave * 32 + mi * 16 + quad * 4 + r;
#pragma unroll
      for (int di = 0; di < 5; ++di) {
        int e = h * HD + di * 16 + r16;
        attn_out[(size_t)tok * EMBED + e] = (_Float16)(o[mi][di][r] * inv);
      }
    }
}

// ---------------- launch ----------------
extern "C" void kernel_launch(void* const* d_in, const int* in_sizes, int n_in,
                              void* d_out, int out_size, void* d_ws, size_t ws_size,
                              hipStream_t stream) {
  const float* hidden = (const float*)d_in[0];
  const float* w_qkv  = (const float*)d_in[1];
  const float* b_qkv  = (const float*)d_in[2];
  const float* w_proj = (const float*)d_in[3];
  const float* b_proj = (const float*)d_in[4];
  float* out = (float*)d_out;

  char* ws = (char*)d_ws;
  size_t off = 0;
  _Float16* hidden_h = (_Float16*)(ws + off); off += (size_t)MTOK * EMBED * 2;
  _Float16* wqkv_t   = (_Float16*)(ws + off); off += (size_t)NQKV * EMBED * 2;
  _Float16* wproj_t  = (_Float16*)(ws + off); off += (size_t)EMBED * EMBED * 2;
  _Float16* q_pad    = (_Float16*)(ws + off); off += (size_t)BATCH * NH * SEQ * HDP * 2;
  _Float16* k_pad    = (_Float16*)(ws + off); off += (size_t)BATCH * NH * SEQ * HDP * 2;
  _Float16* v_t      = (_Float16*)(ws + off); off += (size_t)BATCH * NH * HD * SEQ * 2;
  _Float16* attn_out = hidden_h;  // alias: hidden_h consumed before attention writes

  {
    int n4 = MTOK * EMBED / 4;
    cvt_f32_to_f16<<<(n4 + 255) / 256, 256, 0, stream>>>((const float4*)hidden, hidden_h, n4);
  }
  cvt_transpose_f16<NQKV><<<dim3(NQKV / 32, 1280 / 32), 256, 0, stream>>>(w_qkv, wqkv_t);
  cvt_transpose_f16<EMBED><<<dim3(EMBED / 32, 1280 / 32), 256, 0, stream>>>(w_proj, wproj_t);

  // QKV projection: M=16384, N=3840 -> 64 x 15 = 960 blocks (960 % 8 == 0)
  gemm256<0><<<960, 512, 0, stream>>>(hidden_h, wqkv_t, b_qkv, q_pad, k_pad, v_t, nullptr);

  attn_kernel<<<BATCH * NH * (SEQ / 128), 256, 0, stream>>>(q_pad, k_pad, v_t, attn_out);

  // output projection: M=16384, N=1280 -> 64 x 5 = 320 blocks (320 % 8 == 0)
  gemm256<1><<<320, 512, 0, stream>>>(attn_out, wproj_t, b_proj, nullptr, nullptr, nullptr, out);
}